// Round 5
// baseline (247.853 us; speedup 1.0000x reference)
//
#include <hip/hip_runtime.h>

typedef __bf16 bf16_t;
typedef __bf16 bf16x8 __attribute__((ext_vector_type(8)));
typedef float  f32x4  __attribute__((ext_vector_type(4)));

#define HEADS 8
#define HEAD_DIM 32
#define DIM 256
#define BL 10
#define SEQ 1024
#define M_TOTAL (BL*SEQ)
#define QK_SCALE 0.17677669529663687f  // 1/sqrt(32)
#define NPOS (63*63)                    // 3969 distinct (dy,dx) pairs

// element-level XOR swizzle for 64-elem (128B) bf16 rows: kills the
// 16-way bank conflict on stride-128B ds_read_b128 (guide G4).
__device__ __forceinline__ int swz_idx(int row, int col) {
  return row*64 + (col ^ ((row & 7) << 3));
}

// ---------------- prep: weight transposes f32 -> bf16 ----------------
__global__ __launch_bounds__(256) void prep_kernel(
    const float* __restrict__ Wq, const float* __restrict__ Wk, const float* __restrict__ Wv,
    const float* __restrict__ Wo, const float* __restrict__ Wg,
    bf16_t* __restrict__ wqt, bf16_t* __restrict__ wkt, bf16_t* __restrict__ wvt,
    bf16_t* __restrict__ wot, bf16_t* __restrict__ wg1t, bf16_t* __restrict__ wg2t)
{
  const int NW = 65536;
  for (int i = blockIdx.x*blockDim.x + threadIdx.x; i < 6*NW; i += gridDim.x*blockDim.x) {
    const int a = i >> 16, idx = i & 65535, n = idx >> 8, k = idx & 255;
    switch (a) {
      case 0: wqt[idx]  = (bf16_t)Wq[k*256+n]; break;
      case 1: wkt[idx]  = (bf16_t)Wk[k*256+n]; break;
      case 2: wvt[idx]  = (bf16_t)Wv[k*256+n]; break;
      case 3: wot[idx]  = (bf16_t)Wo[k*256+n]; break;
      case 4: wg1t[idx] = (bf16_t)Wg[k*256+n]; break;
      case 5: wg2t[idx] = (bf16_t)Wg[(256+k)*256+n]; break;
    }
  }
}

// ---------------- s = relu(x@Ws1+bs1)@Ws2+bs2, f32 ----------------
__global__ __launch_bounds__(256) void s_proj_kernel(
    const float* __restrict__ x, const float* __restrict__ Ws1, const float* __restrict__ bs1,
    const float* __restrict__ Ws2, const float* __restrict__ bs2, float* __restrict__ sf)
{
  const int row = blockIdx.x*blockDim.x + threadIdx.x;
  if (row >= M_TOTAL) return;
  float hid[32];
  #pragma unroll
  for (int m = 0; m < 32; ++m) hid[m] = bs1[m];
  const float* xr = x + (size_t)row*DIM;
  for (int k = 0; k < DIM; ++k) {
    const float xv = xr[k];
    const float* w = Ws1 + k*32;
    #pragma unroll
    for (int m = 0; m < 32; ++m) hid[m] = fmaf(xv, w[m], hid[m]);
  }
  float sv[8];
  #pragma unroll
  for (int t = 0; t < 8; ++t) sv[t] = bs2[t];
  #pragma unroll
  for (int m = 0; m < 32; ++m) {
    const float hv = fmaxf(hid[m], 0.f);
    #pragma unroll
    for (int t = 0; t < 8; ++t) sv[t] = fmaf(hv, Ws2[m*8+t], sv[t]);
  }
  #pragma unroll
  for (int t = 0; t < 8; ++t) sf[(size_t)row*8+t] = sv[t];
}

// ---------------- pos table: 63x63 (dy,dx) -> 8 heads, f32 ----------------
__global__ __launch_bounds__(256) void pos_tab_kernel(
    const float* __restrict__ Wp1, const float* __restrict__ bp1,
    const float* __restrict__ Wp2, const float* __restrict__ bp2,
    float* __restrict__ posT)
{
  __shared__ float w1[96], b1[32], w2[256], b2[8];
  const int tid = threadIdx.x;
  if (tid < 96) w1[tid] = Wp1[tid];
  if (tid < 32) b1[tid] = bp1[tid];
  w2[tid] = Wp2[tid];
  if (tid < 8)  b2[tid] = bp2[tid];
  __syncthreads();
  const int p = blockIdx.x*256 + tid;
  if (p >= NPOS) return;
  const float dy = (float)(p / 63 - 31);
  const float dx = (float)(p % 63 - 31);
  const float dist = sqrtf(dy*dy + dx*dx);
  float o[8];
  #pragma unroll
  for (int t = 0; t < 8; ++t) o[t] = b2[t];
  #pragma unroll
  for (int m = 0; m < 32; ++m) {
    float hv = fmaf(dy, w1[m], fmaf(dx, w1[32+m], fmaf(dist, w1[64+m], b1[m])));
    hv = fmaxf(hv, 0.f);
    #pragma unroll
    for (int t = 0; t < 8; ++t) o[t] = fmaf(hv, w2[m*8+t], o[t]);
  }
  #pragma unroll
  for (int t = 0; t < 8; ++t) posT[t*NPOS + p] = o[t];
}

// ---------------- GEMM: out = bf16(scale*(A[M][256]@BT^T + bias)) ----------------
// AF32=1: A is f32 (converted inline). AF32=0: A is bf16.
template<int AF32>
__global__ __launch_bounds__(256) void gemm_bias_kernel(
    const void* __restrict__ Aptr, const bf16_t* __restrict__ BT,
    const float* __restrict__ bias, bf16_t* __restrict__ out, float scale)
{
  const int mt = blockIdx.x, ngb = blockIdx.y;
  const int tid = threadIdx.x;
  const int w = tid >> 6, lane = tid & 63, g = lane >> 4, l15 = lane & 15;
  const int arow = mt*64 + w*16 + l15;
  bf16x8 af[8];
  if (AF32) {
    const float4* Arow = (const float4*)((const float*)Aptr + (size_t)arow*DIM);
    #pragma unroll
    for (int kc = 0; kc < 8; ++kc) {   // k = kc*32 + g*8 .. +8
      const float4 f0 = Arow[kc*8 + g*2], f1 = Arow[kc*8 + g*2 + 1];
      bf16x8 v;
      v[0]=(bf16_t)f0.x; v[1]=(bf16_t)f0.y; v[2]=(bf16_t)f0.z; v[3]=(bf16_t)f0.w;
      v[4]=(bf16_t)f1.x; v[5]=(bf16_t)f1.y; v[6]=(bf16_t)f1.z; v[7]=(bf16_t)f1.w;
      af[kc] = v;
    }
  } else {
    const bf16x8* Arow = (const bf16x8*)((const bf16_t*)Aptr + (size_t)arow*DIM);
    #pragma unroll
    for (int kc = 0; kc < 8; ++kc) af[kc] = Arow[kc*4 + g];
  }
  #pragma unroll
  for (int c = 0; c < 4; ++c) {
    const int n = ngb*64 + c*16 + l15;
    const bf16x8* Brow = (const bf16x8*)(BT + (size_t)n*DIM);
    f32x4 acc = {0.f,0.f,0.f,0.f};
    #pragma unroll
    for (int kc = 0; kc < 8; ++kc)
      acc = __builtin_amdgcn_mfma_f32_16x16x32_bf16(af[kc], Brow[kc*4+g], acc, 0, 0, 0);
    const float bv = bias[n];
    #pragma unroll
    for (int r = 0; r < 4; ++r) {
      const int row = mt*64 + w*16 + g*4 + r;   // D: row=(lane>>4)*4+r, col=lane&15
      out[(size_t)row*DIM + n] = (bf16_t)((acc[r] + bv)*scale);
    }
  }
}

// ---------------- flash attention ----------------
// logits = scale*q.k + s_i.s_j + pos(dy,dx); fsim folded into QK via
// 64-wide ext rows [q*scale(32) | s(8) | 0(24)].
__global__ __launch_bounds__(256) void attn_kernel(
    const bf16_t* __restrict__ qb, const bf16_t* __restrict__ kb,
    const bf16_t* __restrict__ vb, const float* __restrict__ sf,
    const float* __restrict__ posT, bf16_t* __restrict__ att)
{
  __shared__ __align__(16) bf16_t lq[64*64];
  __shared__ __align__(16) bf16_t lk[64*64];
  __shared__ __align__(16) bf16_t lp[64*64];
  __shared__ __align__(16) bf16_t lv[32*64];
  __shared__ float ptab[NPOS];

  const int it = blockIdx.x, h = blockIdx.y, b = blockIdx.z;
  const int i0 = it*64;
  const int tid = threadIdx.x;
  const int w = tid >> 6, lane = tid & 63, g = lane >> 4, l15 = lane & 15;

  for (int p = tid; p < NPOS; p += 256) ptab[p] = posT[h*NPOS + p];

  // ---- stage Q tile (64 rows x 64 ext-dims) ----
  {
    const int r = tid >> 2, q4 = tid & 3;
    const int grow = b*SEQ + i0 + r;
    #pragma unroll
    for (int cc = 0; cc < 2; ++cc) {
      const int ch = q4*2 + cc;
      bf16x8 v;
      if (ch < 4) {
        v = *(const bf16x8*)(qb + (size_t)grow*DIM + h*HEAD_DIM + ch*8);
      } else if (ch == 4) {
        const float* sp = sf + (size_t)grow*8;
        #pragma unroll
        for (int e = 0; e < 8; ++e) v[e] = (bf16_t)sp[e];
      } else {
        #pragma unroll
        for (int e = 0; e < 8; ++e) v[e] = (bf16_t)0.f;
      }
      *(bf16x8*)&lq[swz_idx(r, ch*8)] = v;
    }
  }
  __syncthreads();

  const int qrow = w*16 + l15;
  const bf16x8 aq0 = *(const bf16x8*)&lq[swz_idx(qrow, g*8)];
  const bf16x8 aq1 = *(const bf16x8*)&lq[swz_idx(qrow, 32 + g*8)];

  f32x4 accO0 = {0.f,0.f,0.f,0.f}, accO1 = {0.f,0.f,0.f,0.f};
  float mrow[4], lrow[4];
  #pragma unroll
  for (int r = 0; r < 4; ++r) { mrow[r] = -1e30f; lrow[r] = 0.f; }

  for (int jt = 0; jt < 16; ++jt) {
    const int j0 = jt*64;
    __syncthreads();   // protect lk/lv from previous iteration's readers
    // ---- stage K tile ----
    {
      const int r = tid >> 2, q4 = tid & 3;
      const int grow = b*SEQ + j0 + r;
      #pragma unroll
      for (int cc = 0; cc < 2; ++cc) {
        const int ch = q4*2 + cc;
        bf16x8 v;
        if (ch < 4) {
          v = *(const bf16x8*)(kb + (size_t)grow*DIM + h*HEAD_DIM + ch*8);
        } else if (ch == 4) {
          const float* sp = sf + (size_t)grow*8;
          #pragma unroll
          for (int e = 0; e < 8; ++e) v[e] = (bf16_t)sp[e];
        } else {
          #pragma unroll
          for (int e = 0; e < 8; ++e) v[e] = (bf16_t)0.f;
        }
        *(bf16x8*)&lk[swz_idx(r, ch*8)] = v;
      }
    }
    // ---- stage V transposed: lv[d][j] ----
    {
      const int j = tid >> 2, q4 = tid & 3;
      const bf16x8 v = *(const bf16x8*)(vb + (size_t)(b*SEQ + j0 + j)*DIM + h*HEAD_DIM + q4*8);
      #pragma unroll
      for (int e = 0; e < 8; ++e) {
        const int d = q4*8 + e;
        lv[d*64 + (j ^ ((d & 7) << 3))] = v[e];
      }
    }
    __syncthreads();

    // ---- QK^T (K=64 incl. fsim fold) ----
    f32x4 s4[4];
    #pragma unroll
    for (int c = 0; c < 4; ++c) {
      const int krow = c*16 + l15;
      const bf16x8 bk0 = *(const bf16x8*)&lk[swz_idx(krow, g*8)];
      const bf16x8 bk1 = *(const bf16x8*)&lk[swz_idx(krow, 32 + g*8)];
      f32x4 acc = {0.f,0.f,0.f,0.f};
      acc = __builtin_amdgcn_mfma_f32_16x16x32_bf16(aq0, bk0, acc, 0, 0, 0);
      acc = __builtin_amdgcn_mfma_f32_16x16x32_bf16(aq1, bk1, acc, 0, 0, 0);
      s4[c] = acc;
    }

    // ---- + pos_w via (dy,dx) table lookup (f32) ----
    const int ib = i0 + w*16 + g*4;
    #pragma unroll
    for (int r = 0; r < 4; ++r) {
      const int iy = (ib + r) >> 5, ix = (ib + r) & 31;
      #pragma unroll
      for (int c = 0; c < 4; ++c) {
        const int j = j0 + c*16 + l15;
        const int dy = iy - (j >> 5), dx = ix - (j & 31);
        s4[c][r] += ptab[(dy + 31)*63 + (dx + 31)];
      }
    }

    // ---- online softmax (16-lane groups hold one row set) ----
    float pmax[4];
    #pragma unroll
    for (int r = 0; r < 4; ++r)
      pmax[r] = fmaxf(fmaxf(s4[0][r], s4[1][r]), fmaxf(s4[2][r], s4[3][r]));
    #pragma unroll
    for (int mk = 1; mk <= 8; mk <<= 1) {
      #pragma unroll
      for (int r = 0; r < 4; ++r)
        pmax[r] = fmaxf(pmax[r], __shfl_xor(pmax[r], mk));
    }
    float alpha[4];
    #pragma unroll
    for (int r = 0; r < 4; ++r) {
      const float mn = fmaxf(mrow[r], pmax[r]);
      alpha[r] = __expf(mrow[r] - mn);
      mrow[r] = mn;
    }
    float rsum[4];
    #pragma unroll
    for (int r = 0; r < 4; ++r) {
      #pragma unroll
      for (int c = 0; c < 4; ++c) s4[c][r] = __expf(s4[c][r] - mrow[r]);
      rsum[r] = (s4[0][r] + s4[1][r]) + (s4[2][r] + s4[3][r]);
    }
    #pragma unroll
    for (int mk = 1; mk <= 8; mk <<= 1) {
      #pragma unroll
      for (int r = 0; r < 4; ++r)
        rsum[r] += __shfl_xor(rsum[r], mk);
    }
    #pragma unroll
    for (int r = 0; r < 4; ++r) {
      lrow[r] = lrow[r]*alpha[r] + rsum[r];
      accO0[r] *= alpha[r];
      accO1[r] *= alpha[r];
    }

    // ---- P -> LDS (wave-local rows only) ----
    #pragma unroll
    for (int c = 0; c < 4; ++c) {
      #pragma unroll
      for (int r = 0; r < 4; ++r)
        lp[swz_idx(w*16 + g*4 + r, c*16 + l15)] = (bf16_t)s4[c][r];
    }

    // ---- PV ----
    const int prow = w*16 + l15;
    #pragma unroll
    for (int kc = 0; kc < 2; ++kc) {
      const bf16x8 ap  = *(const bf16x8*)&lp[swz_idx(prow, kc*32 + g*8)];
      const bf16x8 bv0 = *(const bf16x8*)&lv[swz_idx(l15,      kc*32 + g*8)];
      const bf16x8 bv1 = *(const bf16x8*)&lv[swz_idx(16 + l15, kc*32 + g*8)];
      accO0 = __builtin_amdgcn_mfma_f32_16x16x32_bf16(ap, bv0, accO0, 0, 0, 0);
      accO1 = __builtin_amdgcn_mfma_f32_16x16x32_bf16(ap, bv1, accO1, 0, 0, 0);
    }
  }

  // ---- epilogue ----
  #pragma unroll
  for (int r = 0; r < 4; ++r) {
    const int row = b*SEQ + i0 + w*16 + g*4 + r;
    const float inv = 1.f / lrow[r];
    att[(size_t)row*DIM + h*HEAD_DIM + l15]      = (bf16_t)(accO0[r]*inv);
    att[(size_t)row*DIM + h*HEAD_DIM + 16 + l15] = (bf16_t)(accO1[r]*inv);
  }
}

// ---------------- gate: sigmoid([x|prj]@Wg+bg), blend, **f32 out** ----------------
__global__ __launch_bounds__(256) void gate_kernel(
    const float* __restrict__ x, const bf16_t* __restrict__ prj,
    const bf16_t* __restrict__ wg1t, const bf16_t* __restrict__ wg2t,
    const float* __restrict__ bg, float* __restrict__ outp)
{
  const int mt = blockIdx.x, ngb = blockIdx.y;
  const int tid = threadIdx.x;
  const int w = tid >> 6, lane = tid & 63, g = lane >> 4, l15 = lane & 15;
  const int arow = mt*64 + w*16 + l15;
  const float4*  axr = (const float4*)(x + (size_t)arow*DIM);
  const bf16x8*  apr = (const bf16x8*)(prj + (size_t)arow*DIM);
  bf16x8 ax[8], ap[8];
  #pragma unroll
  for (int kc = 0; kc < 8; ++kc) {
    const float4 f0 = axr[kc*8 + g*2], f1 = axr[kc*8 + g*2 + 1];
    bf16x8 v;
    v[0]=(bf16_t)f0.x; v[1]=(bf16_t)f0.y; v[2]=(bf16_t)f0.z; v[3]=(bf16_t)f0.w;
    v[4]=(bf16_t)f1.x; v[5]=(bf16_t)f1.y; v[6]=(bf16_t)f1.z; v[7]=(bf16_t)f1.w;
    ax[kc] = v;
    ap[kc] = apr[kc*4+g];
  }
  #pragma unroll
  for (int c = 0; c < 4; ++c) {
    const int n = ngb*64 + c*16 + l15;
    const bf16x8* b1 = (const bf16x8*)(wg1t + (size_t)n*DIM);
    const bf16x8* b2 = (const bf16x8*)(wg2t + (size_t)n*DIM);
    f32x4 acc = {0.f,0.f,0.f,0.f};
    #pragma unroll
    for (int kc = 0; kc < 8; ++kc)
      acc = __builtin_amdgcn_mfma_f32_16x16x32_bf16(ax[kc], b1[kc*4+g], acc, 0, 0, 0);
    #pragma unroll
    for (int kc = 0; kc < 8; ++kc)
      acc = __builtin_amdgcn_mfma_f32_16x16x32_bf16(ap[kc], b2[kc*4+g], acc, 0, 0, 0);
    const float bv = bg[n];
    #pragma unroll
    for (int r = 0; r < 4; ++r) {
      const int row = mt*64 + w*16 + g*4 + r;
      const float gate = 1.f / (1.f + __expf(-(acc[r] + bv)));
      const float pv = (float)prj[(size_t)row*DIM + n];
      const float xv = x[(size_t)row*DIM + n];
      outp[(size_t)row*DIM + n] = gate*pv + (1.f - gate)*xv;   // f32 store
    }
  }
}

extern "C" void kernel_launch(void* const* d_in, const int* in_sizes, int n_in,
                              void* d_out, int out_size, void* d_ws, size_t ws_size,
                              hipStream_t stream)
{
  const float* x   = (const float*)d_in[0];
  const float* Wq  = (const float*)d_in[1];
  const float* bq  = (const float*)d_in[2];
  const float* Wk  = (const float*)d_in[3];
  const float* bk  = (const float*)d_in[4];
  const float* Wv  = (const float*)d_in[5];
  const float* bv  = (const float*)d_in[6];
  const float* Wp1 = (const float*)d_in[7];
  const float* bp1 = (const float*)d_in[8];
  const float* Wp2 = (const float*)d_in[9];
  const float* bp2 = (const float*)d_in[10];
  const float* Ws1 = (const float*)d_in[11];
  const float* bs1 = (const float*)d_in[12];
  const float* Ws2 = (const float*)d_in[13];
  const float* bs2 = (const float*)d_in[14];
  const float* Wo  = (const float*)d_in[15];
  const float* bo  = (const float*)d_in[16];
  const float* Wg  = (const float*)d_in[17];
  const float* bg  = (const float*)d_in[18];

  char* ws = (char*)d_ws;
  size_t off = 0;
  auto alloc = [&](size_t bytes) {
    char* p = ws + off;
    off += (bytes + 255) & ~(size_t)255;
    return p;
  };
  bf16_t* qbuf = (bf16_t*)alloc((size_t)M_TOTAL*DIM*2);   // 5.24 MB
  bf16_t* kbuf = (bf16_t*)alloc((size_t)M_TOTAL*DIM*2);
  bf16_t* vbuf = (bf16_t*)alloc((size_t)M_TOTAL*DIM*2);
  bf16_t* att  = (bf16_t*)alloc((size_t)M_TOTAL*DIM*2);
  bf16_t* wqt  = (bf16_t*)alloc(65536*2);
  bf16_t* wkt  = (bf16_t*)alloc(65536*2);
  bf16_t* wvt  = (bf16_t*)alloc(65536*2);
  bf16_t* wot  = (bf16_t*)alloc(65536*2);
  bf16_t* wg1t = (bf16_t*)alloc(65536*2);
  bf16_t* wg2t = (bf16_t*)alloc(65536*2);
  float*  sfb  = (float*)alloc((size_t)M_TOTAL*8*4);      // 0.33 MB
  float*  posT = (float*)alloc((size_t)HEADS*NPOS*4);     // 0.127 MB
  bf16_t* prj  = kbuf;  // kbuf dead after attn; total ws ~= 22.2 MB
  (void)ws_size; (void)in_sizes; (void)n_in; (void)out_size;

  prep_kernel<<<1536, 256, 0, stream>>>(Wq, Wk, Wv, Wo, Wg,
                                        wqt, wkt, wvt, wot, wg1t, wg2t);
  s_proj_kernel<<<M_TOTAL/256, 256, 0, stream>>>(x, Ws1, bs1, Ws2, bs2, sfb);
  pos_tab_kernel<<<(NPOS+255)/256, 256, 0, stream>>>(Wp1, bp1, Wp2, bp2, posT);
  gemm_bias_kernel<1><<<dim3(M_TOTAL/64, 4), 256, 0, stream>>>(x, wqt, bq, qbuf, QK_SCALE);
  gemm_bias_kernel<1><<<dim3(M_TOTAL/64, 4), 256, 0, stream>>>(x, wkt, bk, kbuf, 1.f);
  gemm_bias_kernel<1><<<dim3(M_TOTAL/64, 4), 256, 0, stream>>>(x, wvt, bv, vbuf, 1.f);
  attn_kernel<<<dim3(SEQ/64, HEADS, BL), 256, 0, stream>>>(qbuf, kbuf, vbuf, sfb, posT, att);
  gemm_bias_kernel<0><<<dim3(M_TOTAL/64, 4), 256, 0, stream>>>(att, wot, bo, prj, 1.f);
  gate_kernel<<<dim3(M_TOTAL/64, 4), 256, 0, stream>>>(x, prj, wg1t, wg2t, bg,
                                                       (float*)d_out);
}

// Round 6
// 178.980 us; speedup vs baseline: 1.3848x; 1.3848x over previous
//
#include <hip/hip_runtime.h>

typedef __bf16 bf16_t;
typedef __bf16 bf16x8 __attribute__((ext_vector_type(8)));
typedef float  f32x4  __attribute__((ext_vector_type(4)));

#define HEADS 8
#define HEAD_DIM 32
#define DIM 256
#define BL 10
#define SEQ 1024
#define M_TOTAL (BL*SEQ)
#define QK_SCALE 0.17677669529663687f  // 1/sqrt(32)
#define NPOS (63*63)

// element-level XOR swizzle for 64-elem (128B) bf16 rows
__device__ __forceinline__ int swz_idx(int row, int col) {
  return row*64 + (col ^ ((row & 7) << 3));
}
// same for 256-col rows
__device__ __forceinline__ int swz256(int row, int col) {
  return row*256 + (col ^ ((row & 7) << 3));
}

// ---------------- prep: xb cast, BT_all assembly, wo/wg transposes, bias_all ----------------
__global__ __launch_bounds__(256) void prep_kernel(
    const float* __restrict__ x,
    const float* __restrict__ Wq, const float* __restrict__ Wk, const float* __restrict__ Wv,
    const float* __restrict__ Wo, const float* __restrict__ Wg, const float* __restrict__ Ws1,
    const float* __restrict__ bq, const float* __restrict__ bk, const float* __restrict__ bv,
    const float* __restrict__ bs1,
    bf16_t* __restrict__ xb, bf16_t* __restrict__ btall,
    bf16_t* __restrict__ wot, bf16_t* __restrict__ wg1t, bf16_t* __restrict__ wg2t,
    float* __restrict__ bias_all)
{
  const int NX = M_TOTAL*DIM;
  const int NW = 65536;
  const int total = NX + 6*NW + 8192 + 8192 + 832;
  for (int i = blockIdx.x*blockDim.x + threadIdx.x; i < total; i += gridDim.x*blockDim.x) {
    int idx = i;
    if (idx < NX) { xb[idx] = (bf16_t)x[idx]; continue; }
    idx -= NX;
    if (idx < 6*NW) {
      const int a = idx >> 16, e = idx & 65535, n = e >> 8, k = e & 255;
      switch (a) {
        case 0: btall[n*256 + k]        = (bf16_t)Wq[k*256+n]; break;
        case 1: btall[(256+n)*256 + k]  = (bf16_t)Wk[k*256+n]; break;
        case 2: btall[(512+n)*256 + k]  = (bf16_t)Wv[k*256+n]; break;
        case 3: wot[n*256 + k]          = (bf16_t)Wo[k*256+n]; break;
        case 4: wg1t[n*256 + k]         = (bf16_t)Wg[k*256+n]; break;
        case 5: wg2t[n*256 + k]         = (bf16_t)Wg[(256+k)*256+n]; break;
      }
      continue;
    }
    idx -= 6*NW;
    if (idx < 8192) { const int m = idx >> 8, k = idx & 255;
      btall[(768+m)*256 + k] = (bf16_t)Ws1[k*32+m]; continue; }
    idx -= 8192;
    if (idx < 8192) { btall[(800*256) + idx] = (bf16_t)0.f; continue; }
    idx -= 8192;
    { const int j = idx;
      bias_all[j] = (j < 256) ? bq[j] : (j < 512) ? bk[j-256] :
                    (j < 768) ? bv[j-512] : (j < 800) ? bs1[j-768] : 0.f; }
  }
}

// ---------------- pos table: 63x63 (dy,dx) -> 8 heads, f32 ----------------
__global__ __launch_bounds__(256) void pos_tab_kernel(
    const float* __restrict__ Wp1, const float* __restrict__ bp1,
    const float* __restrict__ Wp2, const float* __restrict__ bp2,
    float* __restrict__ posT)
{
  __shared__ float w1[96], b1[32], w2[256], b2[8];
  const int tid = threadIdx.x;
  if (tid < 96) w1[tid] = Wp1[tid];
  if (tid < 32) b1[tid] = bp1[tid];
  w2[tid] = Wp2[tid];
  if (tid < 8)  b2[tid] = bp2[tid];
  __syncthreads();
  const int p = blockIdx.x*256 + tid;
  if (p >= NPOS) return;
  const float dy = (float)(p / 63 - 31);
  const float dx = (float)(p % 63 - 31);
  const float dist = sqrtf(dy*dy + dx*dx);
  float o[8];
  #pragma unroll
  for (int t = 0; t < 8; ++t) o[t] = b2[t];
  #pragma unroll
  for (int m = 0; m < 32; ++m) {
    float hv = fmaf(dy, w1[m], fmaf(dx, w1[32+m], fmaf(dist, w1[64+m], b1[m])));
    hv = fmaxf(hv, 0.f);
    #pragma unroll
    for (int t = 0; t < 8; ++t) o[t] = fmaf(hv, w2[m*8+t], o[t]);
  }
  #pragma unroll
  for (int t = 0; t < 8; ++t) posT[t*NPOS + p] = o[t];
}

// ---------------- fused QKV + hidden projection ----------------
// grid (160, 13): ngb 0-3 Q (scaled), 4-7 K, 8-11 V, 12 hid=relu(x@Ws1+bs1) f32
__global__ __launch_bounds__(256) void qkv_kernel(
    const bf16_t* __restrict__ xb, const bf16_t* __restrict__ btall,
    const float* __restrict__ bias_all,
    bf16_t* __restrict__ qbuf, bf16_t* __restrict__ kbuf, bf16_t* __restrict__ vbuf,
    float* __restrict__ hidf)
{
  const int mt = blockIdx.x, ngb = blockIdx.y;
  const int tid = threadIdx.x;
  const int w = tid >> 6, lane = tid & 63, g = lane >> 4, l15 = lane & 15;
  const int arow = mt*64 + w*16 + l15;
  const bf16x8* Arow = (const bf16x8*)(xb + (size_t)arow*DIM);
  bf16x8 af[8];
  #pragma unroll
  for (int kc = 0; kc < 8; ++kc) af[kc] = Arow[kc*4 + g];
  const bool ishid = (ngb == 12);
  const int cmax = ishid ? 2 : 4;
  bf16_t* dst = (ngb < 4) ? qbuf : (ngb < 8) ? kbuf : vbuf;
  const int coloff = (ngb & 3) * 64;
  const float scale = (ngb < 4) ? QK_SCALE : 1.f;
  for (int c = 0; c < cmax; ++c) {
    const int n = ngb*64 + c*16 + l15;        // btall row
    const bf16x8* Brow = (const bf16x8*)(btall + (size_t)n*DIM);
    f32x4 acc = {0.f,0.f,0.f,0.f};
    #pragma unroll
    for (int kc = 0; kc < 8; ++kc)
      acc = __builtin_amdgcn_mfma_f32_16x16x32_bf16(af[kc], Brow[kc*4+g], acc, 0, 0, 0);
    const float bvv = bias_all[n];
    #pragma unroll
    for (int r = 0; r < 4; ++r) {
      const int row = mt*64 + w*16 + g*4 + r;
      const float val = acc[r] + bvv;
      if (ishid) hidf[(size_t)row*32 + c*16 + l15] = fmaxf(val, 0.f);
      else dst[(size_t)row*DIM + coloff + c*16 + l15] = (bf16_t)(val*scale);
    }
  }
}

// ---------------- s2: s = hid@Ws2 + bs2, f32 ----------------
__global__ __launch_bounds__(256) void s2_kernel(
    const float* __restrict__ hidf, const float* __restrict__ Ws2,
    const float* __restrict__ bs2, float* __restrict__ sf)
{
  const int row = blockIdx.x*blockDim.x + threadIdx.x;
  if (row >= M_TOTAL) return;
  const float4* h4 = (const float4*)(hidf + (size_t)row*32);
  float sv[8];
  #pragma unroll
  for (int t = 0; t < 8; ++t) sv[t] = bs2[t];
  #pragma unroll
  for (int mq = 0; mq < 8; ++mq) {
    const float4 h = h4[mq];
    const float hv[4] = {h.x, h.y, h.z, h.w};
    #pragma unroll
    for (int e = 0; e < 4; ++e) {
      #pragma unroll
      for (int t = 0; t < 8; ++t) sv[t] = fmaf(hv[e], Ws2[(mq*4+e)*8+t], sv[t]);
    }
  }
  #pragma unroll
  for (int t = 0; t < 8; ++t) sf[(size_t)row*8+t] = sv[t];
}

// ---------------- flash attention ----------------
__global__ __launch_bounds__(256) void attn_kernel(
    const bf16_t* __restrict__ qb, const bf16_t* __restrict__ kb,
    const bf16_t* __restrict__ vb, const float* __restrict__ sf,
    const float* __restrict__ posT, bf16_t* __restrict__ att)
{
  __shared__ __align__(16) bf16_t lqp[64*64];   // Q staging, then P
  __shared__ __align__(16) bf16_t lk[64*64];
  __shared__ __align__(16) bf16_t lv[48*64];    // rows 0-31 V^T, 32 ones, 33-47 zero
  __shared__ float ptab[33*63];

  const int it = blockIdx.x, h = blockIdx.y, b = blockIdx.z;
  const int i0 = it*64, iy0 = it*2;
  const int tid = threadIdx.x;
  const int w = tid >> 6, lane = tid & 63, g = lane >> 4, l15 = lane & 15;

  // ---- stage pos slice: rows iy0..iy0+32 of the 63x63 table ----
  for (int p = tid; p < 33*63; p += 256) {
    const int rr = p / 63, cc = p - rr*63;
    ptab[p] = posT[h*NPOS + (iy0 + rr)*63 + cc];
  }
  // ---- one-time init of lv rows 32..47 (ones row + zeros) ----
  for (int p = tid; p < 16*64; p += 256) {
    const int d = 32 + (p >> 6), j = p & 63;
    lv[d*64 + (j ^ ((d & 7) << 3))] = (bf16_t)((d == 32) ? 1.f : 0.f);
  }
  // ---- stage Q tile (64 rows x 64 ext-dims) ----
  {
    const int r = tid >> 2, q4 = tid & 3;
    const int grow = b*SEQ + i0 + r;
    #pragma unroll
    for (int cc = 0; cc < 2; ++cc) {
      const int ch = q4*2 + cc;
      bf16x8 v;
      if (ch < 4) {
        v = *(const bf16x8*)(qb + (size_t)grow*DIM + h*HEAD_DIM + ch*8);
      } else if (ch == 4) {
        const float* sp = sf + (size_t)grow*8;
        #pragma unroll
        for (int e = 0; e < 8; ++e) v[e] = (bf16_t)sp[e];
      } else {
        #pragma unroll
        for (int e = 0; e < 8; ++e) v[e] = (bf16_t)0.f;
      }
      *(bf16x8*)&lqp[swz_idx(r, ch*8)] = v;
    }
  }
  __syncthreads();

  const int qrow = w*16 + l15;
  const bf16x8 aq0 = *(const bf16x8*)&lqp[swz_idx(qrow, g*8)];
  const bf16x8 aq1 = *(const bf16x8*)&lqp[swz_idx(qrow, 32 + g*8)];

  f32x4 accO0 = {0.f,0.f,0.f,0.f}, accO1 = {0.f,0.f,0.f,0.f}, accO2 = {0.f,0.f,0.f,0.f};
  float mrow[4];
  #pragma unroll
  for (int r = 0; r < 4; ++r) mrow[r] = -1e30f;

  for (int jt = 0; jt < 16; ++jt) {
    const int j0 = jt*64;
    __syncthreads();
    // ---- stage K tile ----
    {
      const int r = tid >> 2, q4 = tid & 3;
      const int grow = b*SEQ + j0 + r;
      #pragma unroll
      for (int cc = 0; cc < 2; ++cc) {
        const int ch = q4*2 + cc;
        bf16x8 v;
        if (ch < 4) {
          v = *(const bf16x8*)(kb + (size_t)grow*DIM + h*HEAD_DIM + ch*8);
        } else if (ch == 4) {
          const float* sp = sf + (size_t)grow*8;
          #pragma unroll
          for (int e = 0; e < 8; ++e) v[e] = (bf16_t)sp[e];
        } else {
          #pragma unroll
          for (int e = 0; e < 8; ++e) v[e] = (bf16_t)0.f;
        }
        *(bf16x8*)&lk[swz_idx(r, ch*8)] = v;
      }
    }
    // ---- stage V transposed: lv[d][j] ----
    {
      const int j = tid >> 2, q4 = tid & 3;
      const bf16x8 v = *(const bf16x8*)(vb + (size_t)(b*SEQ + j0 + j)*DIM + h*HEAD_DIM + q4*8);
      #pragma unroll
      for (int e = 0; e < 8; ++e) {
        const int d = q4*8 + e;
        lv[d*64 + (j ^ ((d & 7) << 3))] = v[e];
      }
    }
    __syncthreads();

    // ---- QK^T (K=64 incl. fsim fold) ----
    f32x4 s4[4];
    #pragma unroll
    for (int c = 0; c < 4; ++c) {
      const int krow = c*16 + l15;
      const bf16x8 bk0 = *(const bf16x8*)&lk[swz_idx(krow, g*8)];
      const bf16x8 bk1 = *(const bf16x8*)&lk[swz_idx(krow, 32 + g*8)];
      f32x4 acc = {0.f,0.f,0.f,0.f};
      acc = __builtin_amdgcn_mfma_f32_16x16x32_bf16(aq0, bk0, acc, 0, 0, 0);
      acc = __builtin_amdgcn_mfma_f32_16x16x32_bf16(aq1, bk1, acc, 0, 0, 0);
      s4[c] = acc;
    }

    // ---- + pos (f32 slice lookup) ----
    const int ib = i0 + w*16 + g*4;
    #pragma unroll
    for (int r = 0; r < 4; ++r) {
      const int rbase = ((ib + r) >> 5) - iy0 + 31;
      const int ixr = (ib + r) & 31;
      #pragma unroll
      for (int c = 0; c < 4; ++c) {
        const int j = j0 + c*16 + l15;
        s4[c][r] += ptab[(rbase - (j >> 5))*63 + (ixr - (j & 31) + 31)];
      }
    }

    // ---- online softmax: max only (denominator via ones-column MFMA) ----
    float pmax[4];
    #pragma unroll
    for (int r = 0; r < 4; ++r)
      pmax[r] = fmaxf(fmaxf(s4[0][r], s4[1][r]), fmaxf(s4[2][r], s4[3][r]));
    #pragma unroll
    for (int mk = 1; mk <= 8; mk <<= 1) {
      #pragma unroll
      for (int r = 0; r < 4; ++r)
        pmax[r] = fmaxf(pmax[r], __shfl_xor(pmax[r], mk));
    }
    float alpha[4];
    #pragma unroll
    for (int r = 0; r < 4; ++r) {
      const float mn = fmaxf(mrow[r], pmax[r]);
      alpha[r] = __expf(mrow[r] - mn);
      mrow[r] = mn;
    }
    #pragma unroll
    for (int r = 0; r < 4; ++r) {
      #pragma unroll
      for (int c = 0; c < 4; ++c) s4[c][r] = __expf(s4[c][r] - mrow[r]);
      accO0[r] *= alpha[r];
      accO1[r] *= alpha[r];
      accO2[r] *= alpha[r];
    }

    // ---- P -> LDS (wave-local rows only) ----
    #pragma unroll
    for (int c = 0; c < 4; ++c) {
      #pragma unroll
      for (int r = 0; r < 4; ++r)
        lqp[swz_idx(w*16 + g*4 + r, c*16 + l15)] = (bf16_t)s4[c][r];
    }

    // ---- PV (+ ones column accumulates denominator into accO2) ----
    const int prow = w*16 + l15;
    #pragma unroll
    for (int kc = 0; kc < 2; ++kc) {
      const bf16x8 ap  = *(const bf16x8*)&lqp[swz_idx(prow, kc*32 + g*8)];
      const bf16x8 bv0 = *(const bf16x8*)&lv[swz_idx(l15,      kc*32 + g*8)];
      const bf16x8 bv1 = *(const bf16x8*)&lv[swz_idx(16 + l15, kc*32 + g*8)];
      const bf16x8 bv2 = *(const bf16x8*)&lv[swz_idx(32 + l15, kc*32 + g*8)];
      accO0 = __builtin_amdgcn_mfma_f32_16x16x32_bf16(ap, bv0, accO0, 0, 0, 0);
      accO1 = __builtin_amdgcn_mfma_f32_16x16x32_bf16(ap, bv1, accO1, 0, 0, 0);
      accO2 = __builtin_amdgcn_mfma_f32_16x16x32_bf16(ap, bv2, accO2, 0, 0, 0);
    }
  }

  // ---- epilogue: denominator = accO2 col 32 (lane l15==0 of each group) ----
  #pragma unroll
  for (int r = 0; r < 4; ++r) {
    const int row = b*SEQ + i0 + w*16 + g*4 + r;
    const float lsum = __shfl(accO2[r], lane & 48);
    const float inv = 1.f / lsum;
    att[(size_t)row*DIM + h*HEAD_DIM + l15]      = (bf16_t)(accO0[r]*inv);
    att[(size_t)row*DIM + h*HEAD_DIM + 16 + l15] = (bf16_t)(accO1[r]*inv);
  }
}

// ---------------- fused Wo-projection + gate ----------------
// grid (M_TOTAL/16): block = 16 rows x 256 cols; waves split cols (64 each).
__global__ __launch_bounds__(256) void prjgate_kernel(
    const bf16_t* __restrict__ att, const bf16_t* __restrict__ wot,
    const float* __restrict__ bo, const bf16_t* __restrict__ xb,
    const float* __restrict__ x, const bf16_t* __restrict__ wg1t,
    const bf16_t* __restrict__ wg2t, const float* __restrict__ bg,
    float* __restrict__ outp)
{
  __shared__ __align__(16) bf16_t prjT[16*256];   // swizzled, 8 KB
  const int row0 = blockIdx.x * 16;
  const int tid = threadIdx.x;
  const int w = tid >> 6, lane = tid & 63, g = lane >> 4, l15 = lane & 15;
  const int arow = row0 + l15;

  // ---- stage 1: prj = att @ Wo + bo -> LDS (bf16) ----
  {
    const bf16x8* Arow = (const bf16x8*)(att + (size_t)arow*DIM);
    bf16x8 afA[8];
    #pragma unroll
    for (int kc = 0; kc < 8; ++kc) afA[kc] = Arow[kc*4 + g];
    #pragma unroll
    for (int ct = 0; ct < 4; ++ct) {
      const int n = w*64 + ct*16 + l15;
      const bf16x8* Brow = (const bf16x8*)(wot + (size_t)n*DIM);
      f32x4 acc = {0.f,0.f,0.f,0.f};
      #pragma unroll
      for (int kc = 0; kc < 8; ++kc)
        acc = __builtin_amdgcn_mfma_f32_16x16x32_bf16(afA[kc], Brow[kc*4+g], acc, 0, 0, 0);
      const float bvo = bo[n];
      #pragma unroll
      for (int r = 0; r < 4; ++r)
        prjT[swz256(g*4 + r, n)] = (bf16_t)(acc[r] + bvo);
    }
  }
  __syncthreads();

  // ---- stage 2: gate = sigmoid(x@Wg1 + prj@Wg2 + bg); blend; f32 out ----
  const bf16x8* A1r = (const bf16x8*)(xb + (size_t)arow*DIM);
  bf16x8 a1[8], a2[8];
  #pragma unroll
  for (int kc = 0; kc < 8; ++kc) {
    a1[kc] = A1r[kc*4 + g];
    a2[kc] = *(const bf16x8*)&prjT[swz256(l15, kc*32 + g*8)];
  }
  #pragma unroll
  for (int ct = 0; ct < 4; ++ct) {
    const int n = w*64 + ct*16 + l15;
    const bf16x8* b1 = (const bf16x8*)(wg1t + (size_t)n*DIM);
    const bf16x8* b2 = (const bf16x8*)(wg2t + (size_t)n*DIM);
    f32x4 acc = {0.f,0.f,0.f,0.f};
    #pragma unroll
    for (int kc = 0; kc < 8; ++kc)
      acc = __builtin_amdgcn_mfma_f32_16x16x32_bf16(a1[kc], b1[kc*4+g], acc, 0, 0, 0);
    #pragma unroll
    for (int kc = 0; kc < 8; ++kc)
      acc = __builtin_amdgcn_mfma_f32_16x16x32_bf16(a2[kc], b2[kc*4+g], acc, 0, 0, 0);
    const float bgv = bg[n];
    #pragma unroll
    for (int r = 0; r < 4; ++r) {
      const int grow = row0 + g*4 + r;
      const float gate = 1.f / (1.f + __expf(-(acc[r] + bgv)));
      const float pv = (float)prjT[swz256(g*4 + r, n)];
      const float xv = x[(size_t)grow*DIM + n];
      outp[(size_t)grow*DIM + n] = gate*pv + (1.f - gate)*xv;
    }
  }
}

extern "C" void kernel_launch(void* const* d_in, const int* in_sizes, int n_in,
                              void* d_out, int out_size, void* d_ws, size_t ws_size,
                              hipStream_t stream)
{
  const float* x   = (const float*)d_in[0];
  const float* Wq  = (const float*)d_in[1];
  const float* bq  = (const float*)d_in[2];
  const float* Wk  = (const float*)d_in[3];
  const float* bk  = (const float*)d_in[4];
  const float* Wv  = (const float*)d_in[5];
  const float* bv  = (const float*)d_in[6];
  const float* Wp1 = (const float*)d_in[7];
  const float* bp1 = (const float*)d_in[8];
  const float* Wp2 = (const float*)d_in[9];
  const float* bp2 = (const float*)d_in[10];
  const float* Ws1 = (const float*)d_in[11];
  const float* bs1 = (const float*)d_in[12];
  const float* Ws2 = (const float*)d_in[13];
  const float* bs2 = (const float*)d_in[14];
  const float* Wo  = (const float*)d_in[15];
  const float* bo  = (const float*)d_in[16];
  const float* Wg  = (const float*)d_in[17];
  const float* bg  = (const float*)d_in[18];

  char* ws = (char*)d_ws;
  size_t off = 0;
  auto alloc = [&](size_t bytes) {
    char* p = ws + off;
    off += (bytes + 255) & ~(size_t)255;
    return p;
  };
  bf16_t* xb    = (bf16_t*)alloc((size_t)M_TOTAL*DIM*2);   // 5.24 MB
  bf16_t* qbuf  = (bf16_t*)alloc((size_t)M_TOTAL*DIM*2);
  bf16_t* kbuf  = (bf16_t*)alloc((size_t)M_TOTAL*DIM*2);
  bf16_t* vbuf  = (bf16_t*)alloc((size_t)M_TOTAL*DIM*2);
  bf16_t* att   = (bf16_t*)alloc((size_t)M_TOTAL*DIM*2);
  bf16_t* btall = (bf16_t*)alloc((size_t)832*256*2);
  bf16_t* wot   = (bf16_t*)alloc(65536*2);
  bf16_t* wg1t  = (bf16_t*)alloc(65536*2);
  bf16_t* wg2t  = (bf16_t*)alloc(65536*2);
  float*  bias_all = (float*)alloc(832*4);
  float*  hidf  = (float*)alloc((size_t)M_TOTAL*32*4);     // 1.31 MB
  float*  sfb   = (float*)alloc((size_t)M_TOTAL*8*4);
  float*  posT  = (float*)alloc((size_t)HEADS*NPOS*4);
  (void)ws_size; (void)in_sizes; (void)n_in; (void)out_size;

  prep_kernel<<<2048, 256, 0, stream>>>(x, Wq, Wk, Wv, Wo, Wg, Ws1, bq, bk, bv, bs1,
                                        xb, btall, wot, wg1t, wg2t, bias_all);
  pos_tab_kernel<<<(NPOS+255)/256, 256, 0, stream>>>(Wp1, bp1, Wp2, bp2, posT);
  qkv_kernel<<<dim3(M_TOTAL/64, 13), 256, 0, stream>>>(xb, btall, bias_all,
                                                       qbuf, kbuf, vbuf, hidf);
  s2_kernel<<<M_TOTAL/256, 256, 0, stream>>>(hidf, Ws2, bs2, sfb);
  attn_kernel<<<dim3(SEQ/64, HEADS, BL), 256, 0, stream>>>(qbuf, kbuf, vbuf, sfb, posT, att);
  prjgate_kernel<<<M_TOTAL/16, 256, 0, stream>>>(att, wot, bo, xb, x, wg1t, wg2t, bg,
                                                 (float*)d_out);
}

// Round 7
// 167.186 us; speedup vs baseline: 1.4825x; 1.0705x over previous
//
#include <hip/hip_runtime.h>

typedef __bf16 bf16_t;
typedef __bf16 bf16x4 __attribute__((ext_vector_type(4)));
typedef __bf16 bf16x8 __attribute__((ext_vector_type(8)));
typedef float  f32x4  __attribute__((ext_vector_type(4)));

#define HEADS 8
#define HEAD_DIM 32
#define DIM 256
#define BL 10
#define SEQ 1024
#define M_TOTAL (BL*SEQ)
#define QK_SCALE 0.17677669529663687f  // 1/sqrt(32)
#define NPOS (63*63)

__device__ __forceinline__ int swz_idx(int row, int col) {
  return row*64 + (col ^ ((row & 7) << 3));
}
__device__ __forceinline__ int swz256(int row, int col) {
  return row*256 + (col ^ ((row & 7) << 3));
}

// ---------------- cast: xb=bf16(x), Ws1^T -> btall rows 768.., bias_all ----------------
__global__ __launch_bounds__(256) void cast_kernel(
    const float* __restrict__ x, const float* __restrict__ Ws1,
    const float* __restrict__ bq, const float* __restrict__ bk,
    const float* __restrict__ bv, const float* __restrict__ bs1,
    bf16_t* __restrict__ xb, bf16_t* __restrict__ btall, float* __restrict__ bias_all)
{
  const int NX4 = M_TOTAL*DIM/4;   // 655360 float4 items
  const int i = blockIdx.x*blockDim.x + threadIdx.x;
  if (i < NX4) {
    const float4 v = ((const float4*)x)[i];
    bf16x4 o; o[0]=(bf16_t)v.x; o[1]=(bf16_t)v.y; o[2]=(bf16_t)v.z; o[3]=(bf16_t)v.w;
    *(bf16x4*)(xb + (size_t)i*4) = o;
    return;
  }
  int idx = i - NX4;
  if (idx < 8192) {   // btall rows 768..799 = Ws1^T
    const int m = idx >> 8, k = idx & 255;
    btall[(768 + m)*256 + k] = (bf16_t)Ws1[k*32 + m];
    return;
  }
  idx -= 8192;
  if (idx < 832) {
    bias_all[idx] = (idx < 256) ? bq[idx] : (idx < 512) ? bk[idx-256] :
                    (idx < 768) ? bv[idx-512] : (idx < 800) ? bs1[idx-768] : 0.f;
  }
}

// ---------------- LDS tile transpose: 6 weight matrices f32 -> bf16^T ----------------
// grid (4,4,6); block transposes a 64x64 tile.
__global__ __launch_bounds__(256) void trans_kernel(
    const float* __restrict__ Wq, const float* __restrict__ Wk, const float* __restrict__ Wv,
    const float* __restrict__ Wo, const float* __restrict__ Wg,
    bf16_t* __restrict__ btall, bf16_t* __restrict__ wot,
    bf16_t* __restrict__ wg1t, bf16_t* __restrict__ wg2t)
{
  __shared__ float tile[64][65];
  const float* src; bf16_t* dst;
  switch (blockIdx.z) {
    case 0: src = Wq;         dst = btall;          break;
    case 1: src = Wk;         dst = btall + 65536;  break;
    case 2: src = Wv;         dst = btall + 131072; break;
    case 3: src = Wo;         dst = wot;            break;
    case 4: src = Wg;         dst = wg1t;           break;
    default: src = Wg + 65536; dst = wg2t;          break;
  }
  const int bi = blockIdx.x, bj = blockIdx.y;   // k-tile, n-tile
  const int t = threadIdx.x, tr = t >> 4, tc = t & 15;
  #pragma unroll
  for (int i = 0; i < 4; ++i) {
    const float4 v = *(const float4*)(src + (size_t)(bi*64 + tr + 16*i)*256 + bj*64 + tc*4);
    float* tp = &tile[tr + 16*i][tc*4];
    tp[0]=v.x; tp[1]=v.y; tp[2]=v.z; tp[3]=v.w;
  }
  __syncthreads();
  #pragma unroll
  for (int i = 0; i < 4; ++i) {
    bf16x4 o;
    #pragma unroll
    for (int e = 0; e < 4; ++e) o[e] = (bf16_t)tile[tc*4 + e][tr + 16*i];
    *(bf16x4*)(dst + (size_t)(bj*64 + tr + 16*i)*256 + bi*64 + tc*4) = o;
  }
}

// ---------------- pos table: 63x63 (dy,dx) -> 8 heads, f32 ----------------
__global__ __launch_bounds__(256) void pos_tab_kernel(
    const float* __restrict__ Wp1, const float* __restrict__ bp1,
    const float* __restrict__ Wp2, const float* __restrict__ bp2,
    float* __restrict__ posT)
{
  __shared__ float w1[96], b1[32], w2[256], b2[8];
  const int tid = threadIdx.x;
  if (tid < 96) w1[tid] = Wp1[tid];
  if (tid < 32) b1[tid] = bp1[tid];
  w2[tid] = Wp2[tid];
  if (tid < 8)  b2[tid] = bp2[tid];
  __syncthreads();
  const int p = blockIdx.x*256 + tid;
  if (p >= NPOS) return;
  const float dy = (float)(p / 63 - 31);
  const float dx = (float)(p % 63 - 31);
  const float dist = sqrtf(dy*dy + dx*dx);
  float o[8];
  #pragma unroll
  for (int t = 0; t < 8; ++t) o[t] = b2[t];
  #pragma unroll
  for (int m = 0; m < 32; ++m) {
    float hv = fmaf(dy, w1[m], fmaf(dx, w1[32+m], fmaf(dist, w1[64+m], b1[m])));
    hv = fmaxf(hv, 0.f);
    #pragma unroll
    for (int t = 0; t < 8; ++t) o[t] = fmaf(hv, w2[m*8+t], o[t]);
  }
  #pragma unroll
  for (int t = 0; t < 8; ++t) posT[t*NPOS + p] = o[t];
}

// ---------------- fused QKV + hidden projection ----------------
__global__ __launch_bounds__(256) void qkv_kernel(
    const bf16_t* __restrict__ xb, const bf16_t* __restrict__ btall,
    const float* __restrict__ bias_all,
    bf16_t* __restrict__ qbuf, bf16_t* __restrict__ kbuf, bf16_t* __restrict__ vbuf,
    float* __restrict__ hidf)
{
  const int mt = blockIdx.x, ngb = blockIdx.y;
  const int tid = threadIdx.x;
  const int w = tid >> 6, lane = tid & 63, g = lane >> 4, l15 = lane & 15;
  const int arow = mt*64 + w*16 + l15;
  const bf16x8* Arow = (const bf16x8*)(xb + (size_t)arow*DIM);
  bf16x8 af[8];
  #pragma unroll
  for (int kc = 0; kc < 8; ++kc) af[kc] = Arow[kc*4 + g];
  const bool ishid = (ngb == 12);
  const int cmax = ishid ? 2 : 4;
  bf16_t* dst = (ngb < 4) ? qbuf : (ngb < 8) ? kbuf : vbuf;
  const int coloff = (ngb & 3) * 64;
  const float scale = (ngb < 4) ? QK_SCALE : 1.f;
  for (int c = 0; c < cmax; ++c) {
    const int n = ngb*64 + c*16 + l15;
    const bf16x8* Brow = (const bf16x8*)(btall + (size_t)n*DIM);
    f32x4 acc = {0.f,0.f,0.f,0.f};
    #pragma unroll
    for (int kc = 0; kc < 8; ++kc)
      acc = __builtin_amdgcn_mfma_f32_16x16x32_bf16(af[kc], Brow[kc*4+g], acc, 0, 0, 0);
    const float bvv = bias_all[n];
    #pragma unroll
    for (int r = 0; r < 4; ++r) {
      const int row = mt*64 + w*16 + g*4 + r;
      const float val = acc[r] + bvv;
      if (ishid) hidf[(size_t)row*32 + c*16 + l15] = fmaxf(val, 0.f);
      else dst[(size_t)row*DIM + coloff + c*16 + l15] = (bf16_t)(val*scale);
    }
  }
}

// ---------------- s2: s = hid@Ws2 + bs2, f32 ----------------
__global__ __launch_bounds__(256) void s2_kernel(
    const float* __restrict__ hidf, const float* __restrict__ Ws2,
    const float* __restrict__ bs2, float* __restrict__ sf)
{
  const int row = blockIdx.x*blockDim.x + threadIdx.x;
  if (row >= M_TOTAL) return;
  const float4* h4 = (const float4*)(hidf + (size_t)row*32);
  float sv[8];
  #pragma unroll
  for (int t = 0; t < 8; ++t) sv[t] = bs2[t];
  #pragma unroll
  for (int mq = 0; mq < 8; ++mq) {
    const float4 h = h4[mq];
    const float hv[4] = {h.x, h.y, h.z, h.w};
    #pragma unroll
    for (int e = 0; e < 4; ++e) {
      #pragma unroll
      for (int t = 0; t < 8; ++t) sv[t] = fmaf(hv[e], Ws2[(mq*4+e)*8+t], sv[t]);
    }
  }
  #pragma unroll
  for (int t = 0; t < 8; ++t) sf[(size_t)row*8+t] = sv[t];
}

// ---------------- flash attention (XCD-swizzled grid, async reg-staged K/V) ----------------
__global__ __launch_bounds__(256) void attn_kernel(
    const bf16_t* __restrict__ qb, const bf16_t* __restrict__ kb,
    const bf16_t* __restrict__ vb, const float* __restrict__ sf,
    const float* __restrict__ posT, bf16_t* __restrict__ att)
{
  __shared__ __align__(16) bf16_t lqp[64*64];   // Q staging, then P
  __shared__ __align__(16) bf16_t lk[64*64];
  __shared__ __align__(16) bf16_t lv[48*64];    // 0-31 V^T, 32 ones, 33-47 zero
  __shared__ float ptab[33*63];

  // XCD-bijective decode: xcd owns 10 (b,h) pairs -> K/V stays in one L2
  const int wg = blockIdx.x;
  const int xcd = wg & 7, within = wg >> 3;
  const int pair = xcd*10 + (within >> 4);
  const int it = within & 15;
  const int h = pair & 7, b = pair >> 3;
  const int i0 = it*64, iy0 = it*2;
  const int tid = threadIdx.x;
  const int w = tid >> 6, lane = tid & 63, g = lane >> 4, l15 = lane & 15;
  const int r4 = tid >> 2, q4 = tid & 3;

  // ---- issue async loads for jt=0 (K/V/s -> regs) ----
  bf16x8 kreg = *(const bf16x8*)(kb + (size_t)(b*SEQ + r4)*DIM + h*HEAD_DIM + q4*8);
  bf16x8 vreg = *(const bf16x8*)(vb + (size_t)(b*SEQ + r4)*DIM + h*HEAD_DIM + q4*8);
  float4 sA, sB;
  if (tid < 64) {
    const float* sp = sf + (size_t)(b*SEQ + tid)*8;
    sA = *(const float4*)sp; sB = *(const float4*)(sp + 4);
  }

  // ---- stage pos slice ----
  for (int p = tid; p < 33*63; p += 256) {
    const int rr = p / 63, cc = p - rr*63;
    ptab[p] = posT[h*NPOS + (iy0 + rr)*63 + cc];
  }
  // ---- one-time: lv rows 32..47 (ones + zeros), lk zero cols 40..63 ----
  for (int p = tid; p < 16*64; p += 256) {
    const int d = 32 + (p >> 6), j = p & 63;
    lv[d*64 + (j ^ ((d & 7) << 3))] = (bf16_t)((d == 32) ? 1.f : 0.f);
  }
  for (int p = tid; p < 192; p += 256) {
    const int rr = p / 3, ch = 5 + (p % 3);
    bf16x8 z;
    #pragma unroll
    for (int e = 0; e < 8; ++e) z[e] = (bf16_t)0.f;
    *(bf16x8*)&lk[swz_idx(rr, ch*8)] = z;
  }
  // ---- stage Q tile (64 rows x 64 ext-dims) ----
  {
    const int grow = b*SEQ + i0 + r4;
    #pragma unroll
    for (int cc = 0; cc < 2; ++cc) {
      const int ch = q4*2 + cc;
      bf16x8 v;
      if (ch < 4) {
        v = *(const bf16x8*)(qb + (size_t)grow*DIM + h*HEAD_DIM + ch*8);
      } else if (ch == 4) {
        const float* sp = sf + (size_t)grow*8;
        #pragma unroll
        for (int e = 0; e < 8; ++e) v[e] = (bf16_t)sp[e];
      } else {
        #pragma unroll
        for (int e = 0; e < 8; ++e) v[e] = (bf16_t)0.f;
      }
      *(bf16x8*)&lqp[swz_idx(r4, ch*8)] = v;
    }
  }
  __syncthreads();

  const int qrow = w*16 + l15;
  const bf16x8 aq0 = *(const bf16x8*)&lqp[swz_idx(qrow, g*8)];
  const bf16x8 aq1 = *(const bf16x8*)&lqp[swz_idx(qrow, 32 + g*8)];

  f32x4 accO0 = {0.f,0.f,0.f,0.f}, accO1 = {0.f,0.f,0.f,0.f}, accO2 = {0.f,0.f,0.f,0.f};
  float mrow[4];
  #pragma unroll
  for (int r = 0; r < 4; ++r) mrow[r] = -1e30f;

  for (int jt = 0; jt < 16; ++jt) {
    const int j0 = jt*64;
    __syncthreads();             // previous tile's readers done
    // ---- write staged regs -> LDS ----
    *(bf16x8*)&lk[swz_idx(r4, q4*8)] = kreg;
    #pragma unroll
    for (int e = 0; e < 8; ++e) {
      const int d = q4*8 + e;
      lv[d*64 + (r4 ^ ((d & 7) << 3))] = vreg[e];
    }
    if (tid < 64) {
      bf16x8 sv;
      sv[0]=(bf16_t)sA.x; sv[1]=(bf16_t)sA.y; sv[2]=(bf16_t)sA.z; sv[3]=(bf16_t)sA.w;
      sv[4]=(bf16_t)sB.x; sv[5]=(bf16_t)sB.y; sv[6]=(bf16_t)sB.z; sv[7]=(bf16_t)sB.w;
      *(bf16x8*)&lk[swz_idx(tid, 32)] = sv;
    }
    __syncthreads();             // tile jt ready

    // ---- issue async loads for jt+1 (overlap with compute below) ----
    if (jt < 15) {
      const int grow = b*SEQ + j0 + 64 + r4;
      kreg = *(const bf16x8*)(kb + (size_t)grow*DIM + h*HEAD_DIM + q4*8);
      vreg = *(const bf16x8*)(vb + (size_t)grow*DIM + h*HEAD_DIM + q4*8);
      if (tid < 64) {
        const float* sp = sf + (size_t)(b*SEQ + j0 + 64 + tid)*8;
        sA = *(const float4*)sp; sB = *(const float4*)(sp + 4);
      }
    }

    // ---- QK^T (K=64 incl. fsim fold) ----
    f32x4 s4[4];
    #pragma unroll
    for (int c = 0; c < 4; ++c) {
      const int krow = c*16 + l15;
      const bf16x8 bk0 = *(const bf16x8*)&lk[swz_idx(krow, g*8)];
      const bf16x8 bk1 = *(const bf16x8*)&lk[swz_idx(krow, 32 + g*8)];
      f32x4 acc = {0.f,0.f,0.f,0.f};
      acc = __builtin_amdgcn_mfma_f32_16x16x32_bf16(aq0, bk0, acc, 0, 0, 0);
      acc = __builtin_amdgcn_mfma_f32_16x16x32_bf16(aq1, bk1, acc, 0, 0, 0);
      s4[c] = acc;
    }

    // ---- + pos ----
    const int ib = i0 + w*16 + g*4;
    #pragma unroll
    for (int r = 0; r < 4; ++r) {
      const int rbase = ((ib + r) >> 5) - iy0 + 31;
      const int ixr = (ib + r) & 31;
      #pragma unroll
      for (int c = 0; c < 4; ++c) {
        const int j = j0 + c*16 + l15;
        s4[c][r] += ptab[(rbase - (j >> 5))*63 + (ixr - (j & 31) + 31)];
      }
    }

    // ---- online softmax (max only; denom via ones-column) ----
    float pmax[4];
    #pragma unroll
    for (int r = 0; r < 4; ++r)
      pmax[r] = fmaxf(fmaxf(s4[0][r], s4[1][r]), fmaxf(s4[2][r], s4[3][r]));
    #pragma unroll
    for (int mk = 1; mk <= 8; mk <<= 1) {
      #pragma unroll
      for (int r = 0; r < 4; ++r)
        pmax[r] = fmaxf(pmax[r], __shfl_xor(pmax[r], mk));
    }
    float alpha[4];
    #pragma unroll
    for (int r = 0; r < 4; ++r) {
      const float mn = fmaxf(mrow[r], pmax[r]);
      alpha[r] = __expf(mrow[r] - mn);
      mrow[r] = mn;
    }
    #pragma unroll
    for (int r = 0; r < 4; ++r) {
      #pragma unroll
      for (int c = 0; c < 4; ++c) s4[c][r] = __expf(s4[c][r] - mrow[r]);
      accO0[r] *= alpha[r];
      accO1[r] *= alpha[r];
      accO2[r] *= alpha[r];
    }

    // ---- P -> LDS (wave-local rows) ----
    #pragma unroll
    for (int c = 0; c < 4; ++c) {
      #pragma unroll
      for (int r = 0; r < 4; ++r)
        lqp[swz_idx(w*16 + g*4 + r, c*16 + l15)] = (bf16_t)s4[c][r];
    }

    // ---- PV (+ ones column -> denominator in accO2) ----
    const int prow = w*16 + l15;
    #pragma unroll
    for (int kc = 0; kc < 2; ++kc) {
      const bf16x8 ap  = *(const bf16x8*)&lqp[swz_idx(prow, kc*32 + g*8)];
      const bf16x8 bv0 = *(const bf16x8*)&lv[swz_idx(l15,      kc*32 + g*8)];
      const bf16x8 bv1 = *(const bf16x8*)&lv[swz_idx(16 + l15, kc*32 + g*8)];
      const bf16x8 bv2 = *(const bf16x8*)&lv[swz_idx(32 + l15, kc*32 + g*8)];
      accO0 = __builtin_amdgcn_mfma_f32_16x16x32_bf16(ap, bv0, accO0, 0, 0, 0);
      accO1 = __builtin_amdgcn_mfma_f32_16x16x32_bf16(ap, bv1, accO1, 0, 0, 0);
      accO2 = __builtin_amdgcn_mfma_f32_16x16x32_bf16(ap, bv2, accO2, 0, 0, 0);
    }
  }

  // ---- epilogue ----
  #pragma unroll
  for (int r = 0; r < 4; ++r) {
    const int row = b*SEQ + i0 + w*16 + g*4 + r;
    const float lsum = __shfl(accO2[r], lane & 48);
    const float inv = 1.f / lsum;
    att[(size_t)row*DIM + h*HEAD_DIM + l15]      = (bf16_t)(accO0[r]*inv);
    att[(size_t)row*DIM + h*HEAD_DIM + 16 + l15] = (bf16_t)(accO1[r]*inv);
  }
}

// ---------------- fused Wo-projection + gate ----------------
__global__ __launch_bounds__(256) void prjgate_kernel(
    const bf16_t* __restrict__ att, const bf16_t* __restrict__ wot,
    const float* __restrict__ bo, const bf16_t* __restrict__ xb,
    const float* __restrict__ x, const bf16_t* __restrict__ wg1t,
    const bf16_t* __restrict__ wg2t, const float* __restrict__ bg,
    float* __restrict__ outp)
{
  __shared__ __align__(16) bf16_t prjT[16*256];
  const int row0 = blockIdx.x * 16;
  const int tid = threadIdx.x;
  const int w = tid >> 6, lane = tid & 63, g = lane >> 4, l15 = lane & 15;
  const int arow = row0 + l15;

  {
    const bf16x8* Arow = (const bf16x8*)(att + (size_t)arow*DIM);
    bf16x8 afA[8];
    #pragma unroll
    for (int kc = 0; kc < 8; ++kc) afA[kc] = Arow[kc*4 + g];
    #pragma unroll
    for (int ct = 0; ct < 4; ++ct) {
      const int n = w*64 + ct*16 + l15;
      const bf16x8* Brow = (const bf16x8*)(wot + (size_t)n*DIM);
      f32x4 acc = {0.f,0.f,0.f,0.f};
      #pragma unroll
      for (int kc = 0; kc < 8; ++kc)
        acc = __builtin_amdgcn_mfma_f32_16x16x32_bf16(afA[kc], Brow[kc*4+g], acc, 0, 0, 0);
      const float bvo = bo[n];
      #pragma unroll
      for (int r = 0; r < 4; ++r)
        prjT[swz256(g*4 + r, n)] = (bf16_t)(acc[r] + bvo);
    }
  }
  __syncthreads();

  const bf16x8* A1r = (const bf16x8*)(xb + (size_t)arow*DIM);
  bf16x8 a1[8], a2[8];
  #pragma unroll
  for (int kc = 0; kc < 8; ++kc) {
    a1[kc] = A1r[kc*4 + g];
    a2[kc] = *(const bf16x8*)&prjT[swz256(l15, kc*32 + g*8)];
  }
  #pragma unroll
  for (int ct = 0; ct < 4; ++ct) {
    const int n = w*64 + ct*16 + l15;
    const bf16x8* b1 = (const bf16x8*)(wg1t + (size_t)n*DIM);
    const bf16x8* b2 = (const bf16x8*)(wg2t + (size_t)n*DIM);
    f32x4 acc = {0.f,0.f,0.f,0.f};
    #pragma unroll
    for (int kc = 0; kc < 8; ++kc)
      acc = __builtin_amdgcn_mfma_f32_16x16x32_bf16(a1[kc], b1[kc*4+g], acc, 0, 0, 0);
    #pragma unroll
    for (int kc = 0; kc < 8; ++kc)
      acc = __builtin_amdgcn_mfma_f32_16x16x32_bf16(a2[kc], b2[kc*4+g], acc, 0, 0, 0);
    const float bgv = bg[n];
    #pragma unroll
    for (int r = 0; r < 4; ++r) {
      const int grow = row0 + g*4 + r;
      const float gate = 1.f / (1.f + __expf(-(acc[r] + bgv)));
      const float pv = (float)prjT[swz256(g*4 + r, n)];
      const float xv = x[(size_t)grow*DIM + n];
      outp[(size_t)grow*DIM + n] = gate*pv + (1.f - gate)*xv;
    }
  }
}

extern "C" void kernel_launch(void* const* d_in, const int* in_sizes, int n_in,
                              void* d_out, int out_size, void* d_ws, size_t ws_size,
                              hipStream_t stream)
{
  const float* x   = (const float*)d_in[0];
  const float* Wq  = (const float*)d_in[1];
  const float* bq  = (const float*)d_in[2];
  const float* Wk  = (const float*)d_in[3];
  const float* bk  = (const float*)d_in[4];
  const float* Wv  = (const float*)d_in[5];
  const float* bv  = (const float*)d_in[6];
  const float* Wp1 = (const float*)d_in[7];
  const float* bp1 = (const float*)d_in[8];
  const float* Wp2 = (const float*)d_in[9];
  const float* bp2 = (const float*)d_in[10];
  const float* Ws1 = (const float*)d_in[11];
  const float* bs1 = (const float*)d_in[12];
  const float* Ws2 = (const float*)d_in[13];
  const float* bs2 = (const float*)d_in[14];
  const float* Wo  = (const float*)d_in[15];
  const float* bo  = (const float*)d_in[16];
  const float* Wg  = (const float*)d_in[17];
  const float* bg  = (const float*)d_in[18];

  char* ws = (char*)d_ws;
  size_t off = 0;
  auto alloc = [&](size_t bytes) {
    char* p = ws + off;
    off += (bytes + 255) & ~(size_t)255;
    return p;
  };
  bf16_t* xb    = (bf16_t*)alloc((size_t)M_TOTAL*DIM*2);
  bf16_t* qbuf  = (bf16_t*)alloc((size_t)M_TOTAL*DIM*2);
  bf16_t* kbuf  = (bf16_t*)alloc((size_t)M_TOTAL*DIM*2);
  bf16_t* vbuf  = (bf16_t*)alloc((size_t)M_TOTAL*DIM*2);
  bf16_t* att   = (bf16_t*)alloc((size_t)M_TOTAL*DIM*2);
  bf16_t* btall = (bf16_t*)alloc((size_t)800*256*2);
  bf16_t* wot   = (bf16_t*)alloc(65536*2);
  bf16_t* wg1t  = (bf16_t*)alloc(65536*2);
  bf16_t* wg2t  = (bf16_t*)alloc(65536*2);
  float*  bias_all = (float*)alloc(832*4);
  float*  hidf  = (float*)alloc((size_t)M_TOTAL*32*4);
  float*  sfb   = (float*)alloc((size_t)M_TOTAL*8*4);
  float*  posT  = (float*)alloc((size_t)HEADS*NPOS*4);
  (void)ws_size; (void)in_sizes; (void)n_in; (void)out_size;

  const int cast_total = M_TOTAL*DIM/4 + 8192 + 832;
  cast_kernel<<<(cast_total + 255)/256, 256, 0, stream>>>(x, Ws1, bq, bk, bv, bs1,
                                                          xb, btall, bias_all);
  trans_kernel<<<dim3(4,4,6), 256, 0, stream>>>(Wq, Wk, Wv, Wo, Wg,
                                                btall, wot, wg1t, wg2t);
  pos_tab_kernel<<<(NPOS+255)/256, 256, 0, stream>>>(Wp1, bp1, Wp2, bp2, posT);
  qkv_kernel<<<dim3(M_TOTAL/64, 13), 256, 0, stream>>>(xb, btall, bias_all,
                                                       qbuf, kbuf, vbuf, hidf);
  s2_kernel<<<M_TOTAL/256, 256, 0, stream>>>(hidf, Ws2, bs2, sfb);
  attn_kernel<<<SEQ/64*HEADS*BL, 256, 0, stream>>>(qbuf, kbuf, vbuf, sfb, posT, att);
  prjgate_kernel<<<M_TOTAL/16, 256, 0, stream>>>(att, wot, bo, xb, x, wg1t, wg2t, bg,
                                                 (float*)d_out);
}